// Round 1
// baseline (70.444 us; speedup 1.0000x reference)
//
#include <hip/hip_runtime.h>

#define NZ 2048
#define NX 2048
#define NB 4

__global__ __launch_bounds__(256) void wave_cell_kernel(
    const float* __restrict__ h1,
    const float* __restrict__ h2,
    const float* __restrict__ cl,
    const float* __restrict__ bq,
    const float* __restrict__ dtp,
    const float* __restrict__ hp,
    float* __restrict__ out)
{
    const float dt      = dtp[0];
    const float hh      = hp[0];
    const float inv_dt  = 1.0f / dt;
    const float inv_dt2 = inv_dt * inv_dt;
    const float inv_h2  = 1.0f / (hh * hh);

    const int XV  = NX / 4;                     // float4 groups per row
    int tid = blockIdx.x * blockDim.x + threadIdx.x;
    int z   = tid / XV;
    if (z >= NZ) return;
    int xv  = tid - z * XV;
    int x   = xv * 4;
    size_t base = (size_t)z * NX + x;

    // Per-(z,x) coefficient fields, loaded once, reused across batch.
    float4 bv = *(const float4*)(bq + base);
    float4 cv = *(const float4*)(cl + base);

    float den0 = 1.0f / (inv_dt2 + bv.x * inv_dt);
    float den1 = 1.0f / (inv_dt2 + bv.y * inv_dt);
    float den2 = 1.0f / (inv_dt2 + bv.z * inv_dt);
    float den3 = 1.0f / (inv_dt2 + bv.w * inv_dt);

    float k0 = inv_dt2 - bv.x * inv_dt;         // multiplies h2
    float k1 = inv_dt2 - bv.y * inv_dt;
    float k2 = inv_dt2 - bv.z * inv_dt;
    float k3 = inv_dt2 - bv.w * inv_dt;

    float c20 = cv.x * cv.x * inv_h2;           // c^2 / h^2 (fold the /h^2 into c^2)
    float c21 = cv.y * cv.y * inv_h2;
    float c22 = cv.z * cv.z * inv_h2;
    float c23 = cv.w * cv.w * inv_h2;

    const float two_inv_dt2 = 2.0f * inv_dt2;
    const size_t plane = (size_t)NZ * NX;

    float*       outy = out;                    // output 0: y
    float*       outc = out + (size_t)NB * plane; // output 1: copy of h1

    #pragma unroll
    for (int bt = 0; bt < NB; ++bt) {
        const float* p1 = h1 + (size_t)bt * plane;

        float4 ctr = *(const float4*)(p1 + base);
        float4 up, dn;
        if (z > 0)      up = *(const float4*)(p1 + base - NX);
        else            up = make_float4(0.f, 0.f, 0.f, 0.f);
        if (z < NZ - 1) dn = *(const float4*)(p1 + base + NX);
        else            dn = make_float4(0.f, 0.f, 0.f, 0.f);
        float lft = (x > 0)        ? p1[base - 1] : 0.0f;
        float rgt = (x + 4 < NX)   ? p1[base + 4] : 0.0f;

        float4 h2v = *(const float4*)(h2 + (size_t)bt * plane + base);

        // zero-padded 5-point Laplacian (unscaled; /h^2 folded into c2*)
        float lap0 = up.x + dn.x + lft   + ctr.y - 4.0f * ctr.x;
        float lap1 = up.y + dn.y + ctr.x + ctr.z - 4.0f * ctr.y;
        float lap2 = up.z + dn.z + ctr.y + ctr.w - 4.0f * ctr.z;
        float lap3 = up.w + dn.w + ctr.z + rgt   - 4.0f * ctr.w;

        float4 yv;
        yv.x = den0 * (two_inv_dt2 * ctr.x - k0 * h2v.x + c20 * lap0);
        yv.y = den1 * (two_inv_dt2 * ctr.y - k1 * h2v.y + c21 * lap1);
        yv.z = den2 * (two_inv_dt2 * ctr.z - k2 * h2v.z + c22 * lap2);
        yv.w = den3 * (two_inv_dt2 * ctr.w - k3 * h2v.w + c23 * lap3);

        *(float4*)(outy + (size_t)bt * plane + base) = yv;
        *(float4*)(outc + (size_t)bt * plane + base) = ctr;   // output 1 = h1
    }
}

extern "C" void kernel_launch(void* const* d_in, const int* in_sizes, int n_in,
                              void* d_out, int out_size, void* d_ws, size_t ws_size,
                              hipStream_t stream) {
    const float* h1 = (const float*)d_in[0];
    const float* h2 = (const float*)d_in[1];
    const float* cl = (const float*)d_in[2];
    // d_in[3] = rho, unused by the reference
    const float* bq = (const float*)d_in[4];
    const float* dt = (const float*)d_in[5];
    const float* hp = (const float*)d_in[6];
    // d_in[7] = t, d_in[8] = it (unused)
    float* out = (float*)d_out;

    const int total   = NZ * (NX / 4);          // one thread per float4 group
    const int block   = 256;
    const int grid    = (total + block - 1) / block;
    wave_cell_kernel<<<grid, block, 0, stream>>>(h1, h2, cl, bq, dt, hp, out);
}

// Round 2
// 58.367 us; speedup vs baseline: 1.2069x; 1.2069x over previous
//
#include <hip/hip_runtime.h>

#define NZ 2048
#define NX 2048
#define NB 4
#define ZP 4                         // z-rows per thread (register rolling)

typedef float v4f __attribute__((ext_vector_type(4)));

__device__ __forceinline__ v4f ld4(const float* p)   { return *(const v4f*)p; }
__device__ __forceinline__ v4f ldnt4(const float* p) { return __builtin_nontemporal_load((const v4f*)p); }
__device__ __forceinline__ void stnt4(float* p, v4f v){ __builtin_nontemporal_store(v, (v4f*)p); }

__global__ __launch_bounds__(256) void wave_cell_kernel(
    const float* __restrict__ h1,
    const float* __restrict__ h2,
    const float* __restrict__ cl,
    const float* __restrict__ bq,
    const float* __restrict__ dtp,
    const float* __restrict__ hp,
    float* __restrict__ out)
{
    const float dt      = dtp[0];
    const float hh      = hp[0];
    const float inv_dt  = 1.0f / dt;
    const float inv_dt2 = inv_dt * inv_dt;
    const float inv_h2  = 1.0f / (hh * hh);
    const float two_inv_dt2 = 2.0f * inv_dt2;

    const int XV     = NX / 4;       // 512 float4 groups per row
    const int NSTRIP = NZ / ZP;      // 512 strips

    // XCD-aware swizzle: contiguous strip ranges per XCD (grid=1024, %8==0 -> bijective)
    int nbk = gridDim.x;
    int bpx = nbk >> 3;
    int bid = (blockIdx.x & 7) * bpx + (blockIdx.x >> 3);

    int tid   = bid * blockDim.x + threadIdx.x;
    int strip = tid / XV;
    if (strip >= NSTRIP) return;
    int xv = tid - strip * XV;
    int x  = xv * 4;
    int z0 = strip * ZP;
    size_t base0 = (size_t)z0 * NX + x;
    const size_t plane = (size_t)NZ * NX;

    // Per-strip coefficient fields: load once, derive den/k/c2 once, reuse 4 batches.
    v4f den[ZP], kk[ZP], c2[ZP];
    #pragma unroll
    for (int i = 0; i < ZP; ++i) {
        v4f b4 = ld4(bq + base0 + (size_t)i * NX);
        v4f c4 = ld4(cl + base0 + (size_t)i * NX);
        den[i] = 1.0f / (inv_dt2 + b4 * inv_dt);
        kk[i]  = inv_dt2 - b4 * inv_dt;
        c2[i]  = c4 * c4 * inv_h2;
    }

    const v4f vzero = {0.0f, 0.0f, 0.0f, 0.0f};

    // boundary-safe (clamped) offsets so loads stay unconditional/hoistable
    const size_t up_off = (z0 > 0) ? base0 - NX : base0;
    const bool   z_top  = (z0 == 0);
    const bool   x_lo   = (x == 0);
    const bool   x_hi   = (x + 4 == NX);

    #pragma unroll 1
    for (int bt = 0; bt < NB; ++bt) {
        const float* p1 = h1 + (size_t)bt * plane;
        const float* p2 = h2 + (size_t)bt * plane;
        float*       oy = out + (size_t)bt * plane;
        float*       oc = out + (size_t)(NB + bt) * plane;

        v4f up  = ld4(p1 + up_off);
        if (z_top) up = vzero;
        v4f ctr = ld4(p1 + base0);

        #pragma unroll
        for (int iz = 0; iz < ZP; ++iz) {
            const int    z  = z0 + iz;
            const size_t rb = base0 + (size_t)iz * NX;

            const bool z_bot = (z == NZ - 1);
            v4f dn = ld4(p1 + (z_bot ? rb : rb + NX));
            if (z_bot) dn = vzero;

            float lft = p1[x_lo ? rb : rb - 1];
            if (x_lo) lft = 0.0f;
            float rgt = p1[x_hi ? rb : rb + 4];
            if (x_hi) rgt = 0.0f;

            v4f h2v = ldnt4(p2 + rb);

            v4f lap;
            lap.x = up.x + dn.x + lft   + ctr.y - 4.0f * ctr.x;
            lap.y = up.y + dn.y + ctr.x + ctr.z - 4.0f * ctr.y;
            lap.z = up.z + dn.z + ctr.y + ctr.w - 4.0f * ctr.z;
            lap.w = up.w + dn.w + ctr.z + rgt   - 4.0f * ctr.w;

            v4f yv = den[iz] * (two_inv_dt2 * ctr - kk[iz] * h2v + c2[iz] * lap);

            stnt4(oy + rb, yv);
            stnt4(oc + rb, ctr);    // output 1 = copy of h1

            up  = ctr;
            ctr = dn;
        }
    }
}

extern "C" void kernel_launch(void* const* d_in, const int* in_sizes, int n_in,
                              void* d_out, int out_size, void* d_ws, size_t ws_size,
                              hipStream_t stream) {
    const float* h1 = (const float*)d_in[0];
    const float* h2 = (const float*)d_in[1];
    const float* cl = (const float*)d_in[2];
    // d_in[3] = rho, unused by the reference
    const float* bq = (const float*)d_in[4];
    const float* dt = (const float*)d_in[5];
    const float* hp = (const float*)d_in[6];
    // d_in[7] = t, d_in[8] = it (unused)
    float* out = (float*)d_out;

    const int total = (NZ / ZP) * (NX / 4);     // one thread per 4x4-elem column tile
    const int block = 256;
    const int grid  = (total + block - 1) / block;   // 1024, divisible by 8
    wave_cell_kernel<<<grid, block, 0, stream>>>(h1, h2, cl, bq, dt, hp, out);
}

// Round 3
// 47.728 us; speedup vs baseline: 1.4759x; 1.2229x over previous
//
#include <hip/hip_runtime.h>

#define NZ 2048
#define NX 2048
#define NB 4
#define ZP 2                         // z-rows per thread (register rolling)

typedef float v4f __attribute__((ext_vector_type(4)));

__device__ __forceinline__ v4f ld4(const float* p)   { return *(const v4f*)p; }
__device__ __forceinline__ void stnt4(float* p, v4f v){ __builtin_nontemporal_store(v, (v4f*)p); }

__global__ __launch_bounds__(256, 8) void wave_cell_kernel(
    const float* __restrict__ h1,
    const float* __restrict__ h2,
    const float* __restrict__ cl,
    const float* __restrict__ bq,
    const float* __restrict__ dtp,
    const float* __restrict__ hp,
    float* __restrict__ out)
{
    const float dt      = dtp[0];
    const float hh      = hp[0];
    const float inv_dt  = 1.0f / dt;
    const float inv_dt2 = inv_dt * inv_dt;
    const float inv_h2  = 1.0f / (hh * hh);
    const float two_inv_dt2 = 2.0f * inv_dt2;

    const int XV = NX / 4;                         // 512 float4 groups per row

    // XCD swizzle (grid=8192, %8==0 -> bijective): each XCD gets a contiguous
    // chunk of (strip-block, batch) pairs with batch varying fastest, so the
    // 4 batches sharing one z-band's b/c coefficients are dispatch-adjacent.
    int bid = blockIdx.x;
    int swz = (bid & 7) * (gridDim.x >> 3) + (bid >> 3);
    int batch = swz & (NB - 1);
    int sblk  = swz >> 2;

    int gtid  = sblk * 256 + threadIdx.x;          // within-batch thread id
    int strip = gtid >> 9;                         // /XV
    int xv    = gtid & (XV - 1);
    int x     = xv * 4;
    int z0    = strip * ZP;
    size_t base0 = (size_t)z0 * NX + x;
    const size_t plane = (size_t)NZ * NX;

    const float* p1 = h1 + (size_t)batch * plane;
    const float* p2 = h2 + (size_t)batch * plane;
    float*       oy = out + (size_t)batch * plane;
    float*       oc = out + (size_t)(NB + batch) * plane;

    const bool z_top = (z0 == 0);
    const bool z_bot = (z0 + ZP == NZ);
    const bool x_lo  = (x == 0);
    const bool x_hi  = (x + 4 == NX);

    // ---- issue all global loads up front (clamped addresses, unconditional) ----
    v4f up  = ld4(p1 + (z_top ? base0 : base0 - NX));
    v4f ctr = ld4(p1 + base0);
    v4f dn0 = ld4(p1 + base0 + NX);                           // z0+1 <= NZ-1 always
    v4f dn1 = ld4(p1 + (z_bot ? base0 : base0 + 2 * NX));

    float lft0 = p1[x_lo ? base0      : base0 - 1];
    float rgt0 = p1[x_hi ? base0      : base0 + 4];
    float lft1 = p1[x_lo ? base0 + NX : base0 + NX - 1];
    float rgt1 = p1[x_hi ? base0 + NX : base0 + NX + 4];

    v4f h2a = ld4(p2 + base0);
    v4f h2b = ld4(p2 + base0 + NX);

    v4f b0 = ld4(bq + base0);
    v4f b1 = ld4(bq + base0 + NX);
    v4f c0 = ld4(cl + base0);
    v4f c1 = ld4(cl + base0 + NX);

    if (z_top) up  = (v4f){0.f, 0.f, 0.f, 0.f};
    if (z_bot) dn1 = (v4f){0.f, 0.f, 0.f, 0.f};
    if (x_lo) { lft0 = 0.f; lft1 = 0.f; }
    if (x_hi) { rgt0 = 0.f; rgt1 = 0.f; }

    // ---- row 0 ----
    {
        v4f den = 1.0f / (inv_dt2 + b0 * inv_dt);
        v4f kk  = inv_dt2 - b0 * inv_dt;
        v4f c2  = c0 * c0 * inv_h2;
        v4f lap;
        lap.x = up.x + dn0.x + lft0  + ctr.y - 4.0f * ctr.x;
        lap.y = up.y + dn0.y + ctr.x + ctr.z - 4.0f * ctr.y;
        lap.z = up.z + dn0.z + ctr.y + ctr.w - 4.0f * ctr.z;
        lap.w = up.w + dn0.w + ctr.z + rgt0  - 4.0f * ctr.w;
        v4f yv = den * (two_inv_dt2 * ctr - kk * h2a + c2 * lap);
        stnt4(oy + base0, yv);
        stnt4(oc + base0, ctr);
    }

    // ---- row 1 (roll registers) ----
    {
        v4f den = 1.0f / (inv_dt2 + b1 * inv_dt);
        v4f kk  = inv_dt2 - b1 * inv_dt;
        v4f c2  = c1 * c1 * inv_h2;
        v4f lap;
        lap.x = ctr.x + dn1.x + lft1  + dn0.y - 4.0f * dn0.x;
        lap.y = ctr.y + dn1.y + dn0.x + dn0.z - 4.0f * dn0.y;
        lap.z = ctr.z + dn1.z + dn0.y + dn0.w - 4.0f * dn0.z;
        lap.w = ctr.w + dn1.w + dn0.z + rgt1  - 4.0f * dn0.w;
        v4f yv = den * (two_inv_dt2 * dn0 - kk * h2b + c2 * lap);
        stnt4(oy + base0 + NX, yv);
        stnt4(oc + base0 + NX, dn0);
    }
}

extern "C" void kernel_launch(void* const* d_in, const int* in_sizes, int n_in,
                              void* d_out, int out_size, void* d_ws, size_t ws_size,
                              hipStream_t stream) {
    const float* h1 = (const float*)d_in[0];
    const float* h2 = (const float*)d_in[1];
    const float* cl = (const float*)d_in[2];
    // d_in[3] = rho, unused by the reference
    const float* bq = (const float*)d_in[4];
    const float* dt = (const float*)d_in[5];
    const float* hp = (const float*)d_in[6];
    float* out = (float*)d_out;

    const int threads_per_batch = (NZ / ZP) * (NX / 4);   // 524288
    const int blocks_per_batch  = threads_per_batch / 256; // 2048
    const int grid = blocks_per_batch * NB;                // 8192, %8==0
    wave_cell_kernel<<<grid, 256, 0, stream>>>(h1, h2, cl, bq, dt, hp, out);
}